// Round 1
// baseline (3341.903 us; speedup 1.0000x reference)
//
#include <hip/hip_runtime.h>
#include <math.h>

// Problem constants (match reference)
constexpr int N = 10000, E = 100000, G = 64;
constexpr int F = 64, Dk = 256, L = 3;
constexpr int HID = 256, NCLS = 10;

__device__ __forceinline__ float sigmoidf_(float x) {
    return 1.0f / (1.0f + __expf(-x));
}
__device__ __forceinline__ float leakyf_(float v) {
    return v > 0.0f ? v : 0.01f * v;
}

// ---------------------------------------------------------------------------
// Generic GEMM: C[M, ncols] = A[M,256] @ B[256, ldb](cols slice) (+bias)
// Block: 256 threads, ROWS rows per block. grid = (ceil(M/ROWS), ncols/256)
// col-per-thread; A tile staged in LDS, read back as float4 broadcasts.
// ---------------------------------------------------------------------------
template <int ROWS>
__global__ void k_gemm(const float* __restrict__ A,
                       const float* __restrict__ B, int ldb,
                       const float* __restrict__ bias,
                       float* __restrict__ C, int ldc, int M) {
    __shared__ float Ald[ROWS][Dk];
    const int t = threadIdx.x;
    const int r0 = blockIdx.x * ROWS;
    const int rem = M - r0;
    const int nr = rem < ROWS ? rem : ROWS;
    for (int i = 0; i < ROWS; ++i)
        Ald[i][t] = (i < nr) ? A[(size_t)(r0 + i) * Dk + t] : 0.0f;
    __syncthreads();

    const int c = blockIdx.y * 256 + t;
    float acc[ROWS];
    const float bi = bias ? bias[c] : 0.0f;
#pragma unroll
    for (int e = 0; e < ROWS; ++e) acc[e] = bi;

    for (int k = 0; k < Dk; k += 4) {
        const float w0 = B[(size_t)(k + 0) * ldb + c];
        const float w1 = B[(size_t)(k + 1) * ldb + c];
        const float w2 = B[(size_t)(k + 2) * ldb + c];
        const float w3 = B[(size_t)(k + 3) * ldb + c];
#pragma unroll
        for (int e = 0; e < ROWS; ++e) {
            const float4 a = *reinterpret_cast<const float4*>(&Ald[e][k]);
            acc[e] = fmaf(a.x, w0, acc[e]);
            acc[e] = fmaf(a.y, w1, acc[e]);
            acc[e] = fmaf(a.z, w2, acc[e]);
            acc[e] = fmaf(a.w, w3, acc[e]);
        }
    }
    for (int e = 0; e < nr; ++e) C[(size_t)(r0 + e) * ldc + c] = acc[e];
}

// fc: C[M,256] = A[M,64] @ B[64,256] + bias
__global__ void k_fc(const float* __restrict__ A, const float* __restrict__ B,
                     const float* __restrict__ bias, float* __restrict__ C, int M) {
    __shared__ float Ald[32][F];
    const int t = threadIdx.x;
    const int r0 = blockIdx.x * 32;
    const int rem = M - r0;
    const int nr = rem < 32 ? rem : 32;
    for (int i = t; i < 32 * F; i += 256) {
        int r = i >> 6, k = i & 63;
        Ald[r][k] = (r < nr) ? A[(size_t)(r0 + r) * F + k] : 0.0f;
    }
    __syncthreads();
    const int c = t;
    float acc[32];
    const float bi = bias[c];
#pragma unroll
    for (int e = 0; e < 32; ++e) acc[e] = bi;
    for (int k = 0; k < F; k += 4) {
        const float w0 = B[(size_t)(k + 0) * Dk + c];
        const float w1 = B[(size_t)(k + 1) * Dk + c];
        const float w2 = B[(size_t)(k + 2) * Dk + c];
        const float w3 = B[(size_t)(k + 3) * Dk + c];
#pragma unroll
        for (int e = 0; e < 32; ++e) {
            const float4 a = *reinterpret_cast<const float4*>(&Ald[e][k]);
            acc[e] = fmaf(a.x, w0, acc[e]);
            acc[e] = fmaf(a.y, w1, acc[e]);
            acc[e] = fmaf(a.z, w2, acc[e]);
            acc[e] = fmaf(a.w, w3, acc[e]);
        }
    }
    for (int e = 0; e < nr; ++e) C[(size_t)(r0 + e) * Dk + c] = acc[e];
}

// ---------------------------------------------------------------------------
// Fused edge kernel for conv block i:
//   h1 = leaky(xa[dst] + xb[src] + gfc[batch[dst]])       (gfc includes b1)
//   msg = leaky(h1 @ W2 + b2)
//   gpre = msg @ Wg + bg ; lw = sigmoid(gpre)*msg
//   lgl[e,layer] = ||lw||_2 ; nxt[dst] += lw*msg  (atomics)
// 32 edges per block, 256 threads (col-per-thread).
// ---------------------------------------------------------------------------
__global__ void k_edge(const float* __restrict__ xa, const float* __restrict__ xb,
                       const float* __restrict__ gfc,
                       const int* __restrict__ ei, const int* __restrict__ batch,
                       const float* __restrict__ W2, const float* __restrict__ b2,
                       const float* __restrict__ Wg, const float* __restrict__ bg,
                       float* __restrict__ nxt, float* __restrict__ lgl, int layer) {
    __shared__ float tile[32][Dk];     // h1, then msg
    __shared__ int sdst[32], ssrc[32], sgb[32];
    __shared__ float part[4][32];
    const int t = threadIdx.x;
    const int e0 = blockIdx.x * 32;
    if (t < 32) {
        int e = e0 + t;
        int s = ei[e];
        int d = ei[E + e];
        ssrc[t] = s;
        sdst[t] = d;
        sgb[t] = batch[d];
    }
    __syncthreads();
    const int c = t;
    // h1
#pragma unroll 4
    for (int e = 0; e < 32; ++e) {
        float v = xa[(size_t)sdst[e] * Dk + c] + xb[(size_t)ssrc[e] * Dk + c] +
                  gfc[(size_t)sgb[e] * Dk + c];
        tile[e][c] = leakyf_(v);
    }
    __syncthreads();
    // msg = leaky(h1 @ W2 + b2)
    float acc[32];
    {
        const float bi = b2[c];
#pragma unroll
        for (int e = 0; e < 32; ++e) acc[e] = bi;
    }
    for (int k = 0; k < Dk; k += 4) {
        const float w0 = W2[(size_t)(k + 0) * Dk + c];
        const float w1 = W2[(size_t)(k + 1) * Dk + c];
        const float w2 = W2[(size_t)(k + 2) * Dk + c];
        const float w3 = W2[(size_t)(k + 3) * Dk + c];
#pragma unroll
        for (int e = 0; e < 32; ++e) {
            const float4 a = *reinterpret_cast<const float4*>(&tile[e][k]);
            acc[e] = fmaf(a.x, w0, acc[e]);
            acc[e] = fmaf(a.y, w1, acc[e]);
            acc[e] = fmaf(a.z, w2, acc[e]);
            acc[e] = fmaf(a.w, w3, acc[e]);
        }
    }
    __syncthreads();  // all h1 reads done
#pragma unroll
    for (int e = 0; e < 32; ++e) tile[e][c] = leakyf_(acc[e]);  // msg
    __syncthreads();
    // gate pre = msg @ Wg + bg
    {
        const float bi = bg[c];
#pragma unroll
        for (int e = 0; e < 32; ++e) acc[e] = bi;
    }
    for (int k = 0; k < Dk; k += 4) {
        const float w0 = Wg[(size_t)(k + 0) * Dk + c];
        const float w1 = Wg[(size_t)(k + 1) * Dk + c];
        const float w2 = Wg[(size_t)(k + 2) * Dk + c];
        const float w3 = Wg[(size_t)(k + 3) * Dk + c];
#pragma unroll
        for (int e = 0; e < 32; ++e) {
            const float4 a = *reinterpret_cast<const float4*>(&tile[e][k]);
            acc[e] = fmaf(a.x, w0, acc[e]);
            acc[e] = fmaf(a.y, w1, acc[e]);
            acc[e] = fmaf(a.z, w2, acc[e]);
            acc[e] = fmaf(a.w, w3, acc[e]);
        }
    }
    const int lane = t & 63, w = t >> 6;
#pragma unroll
    for (int e = 0; e < 32; ++e) {
        const float m = tile[e][c];
        const float lw = sigmoidf_(acc[e]) * m;
        atomicAdd(&nxt[(size_t)sdst[e] * Dk + c], lw * m);
        float r = lw * lw;
#pragma unroll
        for (int off = 32; off; off >>= 1) r += __shfl_xor(r, off, 64);
        if (lane == 0) part[w][e] = r;
    }
    __syncthreads();
    if (t < 32) {
        float s = part[0][t] + part[1][t] + part[2][t] + part[3][t];
        lgl[(size_t)(e0 + t) * L + layer] = sqrtf(s);
    }
}

// ---------------------------------------------------------------------------
// Readout node pass: gw = sigmoid(xr[n]+gfr[b]); gf_new[b] += gw*x[n];
// gnorm[b] += ||gw||. One wave per node (4 nodes / 256-thread block).
// ---------------------------------------------------------------------------
__global__ void k_readout_node(const float* __restrict__ x, const float* __restrict__ xr,
                               const float* __restrict__ gfr, const int* __restrict__ batch,
                               float* __restrict__ gf_new, float* __restrict__ gnorm) {
    const int t = threadIdx.x;
    const int w = t >> 6, lane = t & 63;
    const int n = blockIdx.x * 4 + w;
    const int b = batch[n];
    float ss = 0.0f;
#pragma unroll
    for (int j = 0; j < 4; ++j) {
        const int c = lane + j * 64;
        const float g = sigmoidf_(xr[(size_t)n * Dk + c] + gfr[(size_t)b * Dk + c]);
        atomicAdd(&gf_new[(size_t)b * Dk + c], g * x[(size_t)n * Dk + c]);
        ss += g * g;
    }
#pragma unroll
    for (int off = 32; off; off >>= 1) ss += __shfl_xor(ss, off, 64);
    if (lane == 0) atomicAdd(&gnorm[b], sqrtf(ss));
}

__global__ void k_cnt(const int* __restrict__ batch, float* __restrict__ gcnt) {
    const int n = blockIdx.x * 256 + threadIdx.x;
    if (n < N) atomicAdd(&gcnt[batch[n]], 1.0f);
}

__global__ void k_ggl(const float* __restrict__ gnorm, const float* __restrict__ gcnt,
                      float* __restrict__ out) {
    const int t = threadIdx.x;  // 64 threads
    float v = gnorm[t] / fmaxf(gcnt[t], 1.0f);
#pragma unroll
    for (int off = 32; off; off >>= 1) v += __shfl_xor(v, off, 64);
    if (t == 0) *out = v * (1.0f / G);
}

// transpose in[rows,cols] -> out[cols,rows]
__global__ void k_transpose(const float* __restrict__ in, float* __restrict__ out,
                            int rows, int cols) {
    const int idx = blockIdx.x * 256 + threadIdx.x;
    if (idx < rows * cols) {
        const int r = idx / cols, c = idx % cols;
        out[(size_t)c * rows + r] = in[(size_t)r * cols + c];
    }
}

// GRU elementwise combine (gi, gh are [G,768]); gf updated in place.
__global__ void k_gru_ew(const float* __restrict__ gi, const float* __restrict__ gh,
                         float* __restrict__ gf) {
    const int g = blockIdx.x, d = threadIdx.x;
    const float* Gi = gi + (size_t)g * 768;
    const float* Gh = gh + (size_t)g * 768;
    const float h = gf[(size_t)g * Dk + d];
    const float r = sigmoidf_(Gi[d] + Gh[d]);
    const float z = sigmoidf_(Gi[256 + d] + Gh[256 + d]);
    const float nn = tanhf(Gi[512 + d] + r * Gh[512 + d]);
    gf[(size_t)g * Dk + d] = (1.0f - z) * nn + z * h;
}

// BatchNorm (training stats over G graphs) -> xn
__global__ void k_bn(const float* __restrict__ gf, const float* __restrict__ bg,
                     const float* __restrict__ bb, float* __restrict__ xn) {
    const int f = threadIdx.x;
    float mu = 0.0f;
    for (int g = 0; g < G; ++g) mu += gf[(size_t)g * Dk + f];
    mu *= (1.0f / G);
    float var = 0.0f;
    for (int g = 0; g < G; ++g) {
        const float d = gf[(size_t)g * Dk + f] - mu;
        var += d * d;
    }
    var *= (1.0f / G);
    const float inv = (1.0f / sqrtf(var + 1e-5f)) * bg[f];
    const float bet = bb[f];
    for (int g = 0; g < G; ++g)
        xn[(size_t)g * Dk + f] = (gf[(size_t)g * Dk + f] - mu) * inv + bet;
}

__global__ void k_clf1(const float* __restrict__ xn, const float* __restrict__ W,
                       const float* __restrict__ b, float* __restrict__ out) {
    __shared__ float row[Dk];
    const int g = blockIdx.x, t = threadIdx.x;
    row[t] = xn[(size_t)g * Dk + t];
    __syncthreads();
    float acc = b[t];
    for (int k = 0; k < Dk; k += 4) {
        const float4 a = *reinterpret_cast<const float4*>(&row[k]);
        acc = fmaf(a.x, W[(size_t)(k + 0) * HID + t], acc);
        acc = fmaf(a.y, W[(size_t)(k + 1) * HID + t], acc);
        acc = fmaf(a.z, W[(size_t)(k + 2) * HID + t], acc);
        acc = fmaf(a.w, W[(size_t)(k + 3) * HID + t], acc);
    }
    out[(size_t)g * HID + t] = leakyf_(acc);
}

__global__ void k_clf2(const float* __restrict__ h, const float* __restrict__ W,
                       const float* __restrict__ b, float* __restrict__ out) {
    __shared__ float row[HID];
    __shared__ float lg[NCLS];
    const int g = blockIdx.x, t = threadIdx.x;
    row[t] = h[(size_t)g * HID + t];
    __syncthreads();
    if (t < NCLS) {
        float acc = b[t];
        for (int k = 0; k < HID; ++k) acc = fmaf(row[k], W[(size_t)k * NCLS + t], acc);
        lg[t] = acc;
    }
    __syncthreads();
    if (t == 0) {
        float m = lg[0];
        for (int i = 1; i < NCLS; ++i) m = fmaxf(m, lg[i]);
        float s = 0.0f;
        for (int i = 0; i < NCLS; ++i) s += expf(lg[i] - m);
        const float ls = logf(s) + m;
        for (int i = 0; i < NCLS; ++i) out[(size_t)g * NCLS + i] = lg[i] - ls;
    }
}

// ---------------------------------------------------------------------------
extern "C" void kernel_launch(void* const* d_in, const int* in_sizes, int n_in,
                              void* d_out, int out_size, void* d_ws, size_t ws_size,
                              hipStream_t stream) {
    const float* x_in  = (const float*)d_in[0];
    const int*   ei    = (const int*)d_in[1];
    const int*   batch = (const int*)d_in[2];
    const float* fc_w  = (const float*)d_in[3];
    const float* fc_b  = (const float*)d_in[4];
    const float* mg1_w = (const float*)d_in[5];
    const float* mg1_b = (const float*)d_in[6];
    const float* mg2_w = (const float*)d_in[7];
    const float* mg2_b = (const float*)d_in[8];
    const float* gate_w = (const float*)d_in[9];
    const float* gate_b = (const float*)d_in[10];
    const float* rd_w  = (const float*)d_in[11];
    const float* rd_b  = (const float*)d_in[12];
    const float* gru_wih = (const float*)d_in[13];
    const float* gru_whh = (const float*)d_in[14];
    const float* gru_bih = (const float*)d_in[15];
    const float* gru_bhh = (const float*)d_in[16];
    const float* bn_g  = (const float*)d_in[17];
    const float* bn_b  = (const float*)d_in[18];
    const float* clf1_w = (const float*)d_in[19];
    const float* clf1_b = (const float*)d_in[20];
    const float* clf2_w = (const float*)d_in[21];
    const float* clf2_b = (const float*)d_in[22];

    float* ws = (float*)d_ws;
    size_t off = 0;
    float* cur0 = ws + off; off += (size_t)N * Dk;
    float* cur1 = ws + off; off += (size_t)N * Dk;
    float* xa   = ws + off; off += (size_t)N * Dk;
    float* xb   = ws + off; off += (size_t)N * Dk;
    float* xr   = ws + off; off += (size_t)N * Dk;
    float* gf   = ws + off; off += (size_t)G * Dk;
    float* gfn  = ws + off; off += (size_t)G * Dk;
    float* gfr  = ws + off; off += (size_t)G * Dk;
    float* gfc  = ws + off; off += (size_t)G * Dk;
    float* giB  = ws + off; off += (size_t)G * 768;
    float* ghB  = ws + off; off += (size_t)G * 768;
    float* gnorm = ws + off; off += G;
    float* gcnt  = ws + off; off += G;
    float* xn   = ws + off; off += (size_t)G * Dk;
    float* hcl  = ws + off; off += (size_t)G * HID;
    float* wihT = ws + off; off += (size_t)768 * Dk;
    float* whhT = ws + off; off += (size_t)768 * Dk;

    float* out_logits = (float*)d_out;
    float* out_lgl = out_logits + (size_t)G * NCLS;
    float* out_ggl = out_lgl + (size_t)E * L;

    hipMemsetAsync(gf, 0, (size_t)G * Dk * 4, stream);
    hipMemsetAsync(gcnt, 0, (size_t)G * 4, stream);
    k_cnt<<<(N + 255) / 256, 256, 0, stream>>>(batch, gcnt);
    k_transpose<<<(768 * Dk + 255) / 256, 256, 0, stream>>>(gru_wih, wihT, 768, Dk);
    k_transpose<<<(768 * Dk + 255) / 256, 256, 0, stream>>>(gru_whh, whhT, 768, Dk);

    k_fc<<<(N + 31) / 32, 256, 0, stream>>>(x_in, fc_w, fc_b, cur0, N);

    float* cur = cur0;
    float* nxt = cur1;

    auto readout = [&](const float* x, int ridx) {
        k_gemm<32><<<dim3((N + 31) / 32, 1), 256, 0, stream>>>(x, rd_w, Dk, nullptr, xr, Dk, N);
        k_gemm<8><<<dim3(G / 8, 1), 256, 0, stream>>>(gf, rd_w + 256 * Dk, Dk, rd_b, gfr, Dk, G);
        hipMemsetAsync(gfn, 0, (size_t)G * Dk * 4, stream);
        hipMemsetAsync(gnorm, 0, (size_t)G * 4, stream);
        k_readout_node<<<N / 4, 256, 0, stream>>>(x, xr, gfr, batch, gfn, gnorm);
        k_gemm<8><<<dim3(G / 8, 3), 256, 0, stream>>>(gfn, wihT, 768, gru_bih, giB, 768, G);
        k_gemm<8><<<dim3(G / 8, 3), 256, 0, stream>>>(gf, whhT, 768, gru_bhh, ghB, 768, G);
        k_gru_ew<<<G, 256, 0, stream>>>(giB, ghB, gf);
        k_ggl<<<1, 64, 0, stream>>>(gnorm, gcnt, out_ggl + ridx);
    };

    for (int i = 0; i < L; ++i) {
        readout(cur, i);
        const float* W1 = mg1_w + (size_t)i * 768 * Dk;
        k_gemm<8><<<dim3(G / 8, 1), 256, 0, stream>>>(gf, W1 + 512 * Dk, Dk, mg1_b + i * Dk, gfc, Dk, G);
        k_gemm<32><<<dim3((N + 31) / 32, 1), 256, 0, stream>>>(cur, W1, Dk, nullptr, xa, Dk, N);
        k_gemm<32><<<dim3((N + 31) / 32, 1), 256, 0, stream>>>(cur, W1 + 256 * Dk, Dk, nullptr, xb, Dk, N);
        hipMemsetAsync(nxt, 0, (size_t)N * Dk * 4, stream);
        k_edge<<<E / 32, 256, 0, stream>>>(xa, xb, gfc, ei, batch,
                                           mg2_w + (size_t)i * Dk * Dk, mg2_b + i * Dk,
                                           gate_w + (size_t)i * Dk * Dk, gate_b + i * Dk,
                                           nxt, out_lgl, i);
        float* tmp = cur; cur = nxt; nxt = tmp;
    }
    readout(cur, L);

    k_bn<<<1, 256, 0, stream>>>(gf, bn_g, bn_b, xn);
    k_clf1<<<G, 256, 0, stream>>>(xn, clf1_w, clf1_b, hcl);
    k_clf2<<<G, 256, 0, stream>>>(hcl, clf2_w, clf2_b, out_logits);
}

// Round 2
// 2605.450 us; speedup vs baseline: 1.2827x; 1.2827x over previous
//
#include <hip/hip_runtime.h>
#include <math.h>

// Problem constants (match reference)
constexpr int N = 10000, E = 100000, G = 64;
constexpr int F = 64, Dk = 256, L = 3;
constexpr int HID = 256, NCLS = 10;

__device__ __forceinline__ float sigmoidf_(float x) {
    return 1.0f / (1.0f + __expf(-x));
}
__device__ __forceinline__ float leakyf_(float v) {
    return v > 0.0f ? v : 0.01f * v;
}

// ---------------------------------------------------------------------------
// Register-tiled fused edge kernel for conv block i:
//   h1  = leaky(xa[dst] + xb[src] + gfc[batch[dst]])   (gfc includes b1)
//   msg = leaky(h1 @ W2 + b2)
//   gp  = msg @ Wg + bg ; lw = sigmoid(gp)*msg
//   lgl[e,layer] = ||lw|| ; nxt[dst] += lw*msg (atomics)
// Block: 256 thr = 4 waves. 32 edges/block. Wave eg owns edges 8*eg..8*eg+7.
// Lane cg = t&63 owns cols 4*cg..4*cg+3. Per-thread acc: float4[8] (VGPRs!).
// W staged per 16-k chunk in LDS; A(tile) reads are wave-uniform broadcasts.
// ---------------------------------------------------------------------------
__global__ __launch_bounds__(256, 3) void k_edge_rt(
    const float* __restrict__ xa, const float* __restrict__ xb,
    const float* __restrict__ gfc, const int* __restrict__ ei,
    const int* __restrict__ batch,
    const float* __restrict__ W2, const float* __restrict__ b2,
    const float* __restrict__ Wg, const float* __restrict__ bg,
    float* __restrict__ nxt, float* __restrict__ lgl, int layer) {
    __shared__ float tile[32][Dk];   // h1, then msg   (32 KB)
    __shared__ float wbuf[16][Dk];   // W k-chunk      (16 KB)
    __shared__ int sdst[32], ssrc[32], sgb[32];

    const int t = threadIdx.x;
    const int e0 = blockIdx.x * 32;
    if (t < 32) {
        const int d = ei[E + e0 + t];
        sdst[t] = d;
        ssrc[t] = ei[e0 + t];
        sgb[t] = batch[d];
    }
    __syncthreads();

    // ---- build h1 tile: 8 threads per row, 8 float4 each ----
    {
        const int r = t >> 3, l8 = t & 7;
        const int d = sdst[r], s = ssrc[r], b = sgb[r];
        const float4* pa = (const float4*)(xa + (size_t)d * Dk);
        const float4* pb = (const float4*)(xb + (size_t)s * Dk);
        const float4* pg = (const float4*)(gfc + (size_t)b * Dk);
        float4* pt = (float4*)(&tile[r][0]);
#pragma unroll
        for (int j = 0; j < 8; ++j) {
            const int ci = l8 + 8 * j;
            const float4 va = pa[ci], vb = pb[ci], vg = pg[ci];
            float4 v;
            v.x = leakyf_(va.x + vb.x + vg.x);
            v.y = leakyf_(va.y + vb.y + vg.y);
            v.z = leakyf_(va.z + vb.z + vg.z);
            v.w = leakyf_(va.w + vb.w + vg.w);
            pt[ci] = v;
        }
    }

    const int cg = t & 63, eg = t >> 6, c0 = cg * 4;
    float4 acc[8];

    // ================= GEMM1: msg = leaky(h1 @ W2 + b2) =================
    {
        const float4 bi = *(const float4*)(b2 + c0);
#pragma unroll
        for (int e = 0; e < 8; ++e) acc[e] = bi;
    }
    for (int k0 = 0; k0 < Dk; k0 += 16) {
        __syncthreads();  // previous wbuf reads done (also covers h1 build @k0=0)
        {   // stage W2[k0..k0+16)[0..256) -> wbuf
            const int kr = t >> 4, l16 = t & 15;
            const float4* s4 = (const float4*)(W2 + (size_t)(k0 + kr) * Dk);
            float4* d4 = (float4*)(&wbuf[kr][0]);
#pragma unroll
            for (int j = 0; j < 4; ++j) d4[l16 + 16 * j] = s4[l16 + 16 * j];
        }
        __syncthreads();
#pragma unroll
        for (int kk = 0; kk < 16; kk += 4) {
            float4 a[8];
#pragma unroll
            for (int e = 0; e < 8; ++e)
                a[e] = *(const float4*)(&tile[8 * eg + e][k0 + kk]);
#pragma unroll
            for (int q = 0; q < 4; ++q) {
                const float4 wv = *(const float4*)(&wbuf[kk + q][c0]);
#pragma unroll
                for (int e = 0; e < 8; ++e) {
                    const float av = (q == 0) ? a[e].x : (q == 1) ? a[e].y
                                   : (q == 2) ? a[e].z : a[e].w;
                    acc[e].x = fmaf(av, wv.x, acc[e].x);
                    acc[e].y = fmaf(av, wv.y, acc[e].y);
                    acc[e].z = fmaf(av, wv.z, acc[e].z);
                    acc[e].w = fmaf(av, wv.w, acc[e].w);
                }
            }
        }
    }
    // msg -> tile (each wave writes only its own 8 rows; cross-wave safety
    // comes from the sync at the top of GEMM2's first chunk)
#pragma unroll
    for (int e = 0; e < 8; ++e) {
        float4 m;
        m.x = leakyf_(acc[e].x);
        m.y = leakyf_(acc[e].y);
        m.z = leakyf_(acc[e].z);
        m.w = leakyf_(acc[e].w);
        *(float4*)(&tile[8 * eg + e][c0]) = m;
    }

    // ================= GEMM2: gp = msg @ Wg + bg =================
    {
        const float4 bi = *(const float4*)(bg + c0);
#pragma unroll
        for (int e = 0; e < 8; ++e) acc[e] = bi;
    }
    for (int k0 = 0; k0 < Dk; k0 += 16) {
        __syncthreads();  // all W2 reads done before overwriting wbuf
        {
            const int kr = t >> 4, l16 = t & 15;
            const float4* s4 = (const float4*)(Wg + (size_t)(k0 + kr) * Dk);
            float4* d4 = (float4*)(&wbuf[kr][0]);
#pragma unroll
            for (int j = 0; j < 4; ++j) d4[l16 + 16 * j] = s4[l16 + 16 * j];
        }
        __syncthreads();
#pragma unroll
        for (int kk = 0; kk < 16; kk += 4) {
            float4 a[8];
#pragma unroll
            for (int e = 0; e < 8; ++e)
                a[e] = *(const float4*)(&tile[8 * eg + e][k0 + kk]);
#pragma unroll
            for (int q = 0; q < 4; ++q) {
                const float4 wv = *(const float4*)(&wbuf[kk + q][c0]);
#pragma unroll
                for (int e = 0; e < 8; ++e) {
                    const float av = (q == 0) ? a[e].x : (q == 1) ? a[e].y
                                   : (q == 2) ? a[e].z : a[e].w;
                    acc[e].x = fmaf(av, wv.x, acc[e].x);
                    acc[e].y = fmaf(av, wv.y, acc[e].y);
                    acc[e].z = fmaf(av, wv.z, acc[e].z);
                    acc[e].w = fmaf(av, wv.w, acc[e].w);
                }
            }
        }
    }

    // ---- epilogue: lw = sigmoid(gp)*msg; scatter lw*msg; lgl = ||lw|| ----
#pragma unroll
    for (int e = 0; e < 8; ++e) {
        const float4 m = *(const float4*)(&tile[8 * eg + e][c0]);
        float4 lw;
        lw.x = sigmoidf_(acc[e].x) * m.x;
        lw.y = sigmoidf_(acc[e].y) * m.y;
        lw.z = sigmoidf_(acc[e].z) * m.z;
        lw.w = sigmoidf_(acc[e].w) * m.w;
        const int d = sdst[8 * eg + e];
        float* base = nxt + (size_t)d * Dk + c0;
        atomicAdd(base + 0, lw.x * m.x);
        atomicAdd(base + 1, lw.y * m.y);
        atomicAdd(base + 2, lw.z * m.z);
        atomicAdd(base + 3, lw.w * m.w);
        float s = lw.x * lw.x + lw.y * lw.y + lw.z * lw.z + lw.w * lw.w;
        s += __shfl_xor(s, 1, 64);
        s += __shfl_xor(s, 2, 64);
        s += __shfl_xor(s, 4, 64);
        s += __shfl_xor(s, 8, 64);
        s += __shfl_xor(s, 16, 64);
        s += __shfl_xor(s, 32, 64);
        if (cg == 0) lgl[(size_t)(e0 + 8 * eg + e) * L + layer] = sqrtf(s);
    }
}

// ---------------------------------------------------------------------------
// Register-tiled node GEMM with NW weight streams sharing one A tile:
//   C_w[M,256] = A[M,256] @ W_w[256,256]   (no bias)
// Same tiling as k_edge_rt. Tail rows handled by clamped stage + predicated
// stores (NO runtime-indexed accumulators).
// ---------------------------------------------------------------------------
template <int NW>
__global__ __launch_bounds__(256, 2) void k_mm(
    const float* __restrict__ A, int M,
    const float* __restrict__ Wa, const float* __restrict__ Wb,
    const float* __restrict__ Wc,
    float* __restrict__ Ca, float* __restrict__ Cb, float* __restrict__ Cc) {
    __shared__ float tile[32][Dk];
    __shared__ float wbuf[NW][16][Dk];
    const int t = threadIdx.x;
    const int r0 = blockIdx.x * 32;

    {   // stage A rows (clamped for tail)
        const int r = t >> 3, l8 = t & 7;
        int row = r0 + r;
        if (row >= M) row = M - 1;
        const float4* pa = (const float4*)(A + (size_t)row * Dk);
        float4* pt = (float4*)(&tile[r][0]);
#pragma unroll
        for (int j = 0; j < 8; ++j) {
            const int ci = l8 + 8 * j;
            pt[ci] = pa[ci];
        }
    }

    const int cg = t & 63, eg = t >> 6, c0 = cg * 4;
    float4 acc[NW][8];
#pragma unroll
    for (int w = 0; w < NW; ++w)
#pragma unroll
        for (int e = 0; e < 8; ++e) acc[w][e] = make_float4(0.f, 0.f, 0.f, 0.f);

    for (int k0 = 0; k0 < Dk; k0 += 16) {
        __syncthreads();
        {
            const int kr = t >> 4, l16 = t & 15;
            const size_t ro = (size_t)(k0 + kr) * Dk;
            {
                const float4* s4 = (const float4*)(Wa + ro);
                float4* d4 = (float4*)(&wbuf[0][kr][0]);
#pragma unroll
                for (int j = 0; j < 4; ++j) d4[l16 + 16 * j] = s4[l16 + 16 * j];
            }
            if constexpr (NW > 1) {
                const float4* s4 = (const float4*)(Wb + ro);
                float4* d4 = (float4*)(&wbuf[1][kr][0]);
#pragma unroll
                for (int j = 0; j < 4; ++j) d4[l16 + 16 * j] = s4[l16 + 16 * j];
            }
            if constexpr (NW > 2) {
                const float4* s4 = (const float4*)(Wc + ro);
                float4* d4 = (float4*)(&wbuf[2][kr][0]);
#pragma unroll
                for (int j = 0; j < 4; ++j) d4[l16 + 16 * j] = s4[l16 + 16 * j];
            }
        }
        __syncthreads();
#pragma unroll
        for (int kk = 0; kk < 16; kk += 4) {
            float4 a[8];
#pragma unroll
            for (int e = 0; e < 8; ++e)
                a[e] = *(const float4*)(&tile[8 * eg + e][k0 + kk]);
#pragma unroll
            for (int q = 0; q < 4; ++q) {
#pragma unroll
                for (int w = 0; w < NW; ++w) {
                    const float4 wv = *(const float4*)(&wbuf[w][kk + q][c0]);
#pragma unroll
                    for (int e = 0; e < 8; ++e) {
                        const float av = (q == 0) ? a[e].x : (q == 1) ? a[e].y
                                       : (q == 2) ? a[e].z : a[e].w;
                        acc[w][e].x = fmaf(av, wv.x, acc[w][e].x);
                        acc[w][e].y = fmaf(av, wv.y, acc[w][e].y);
                        acc[w][e].z = fmaf(av, wv.z, acc[w][e].z);
                        acc[w][e].w = fmaf(av, wv.w, acc[w][e].w);
                    }
                }
            }
        }
    }

#pragma unroll
    for (int e = 0; e < 8; ++e) {
        const int row = r0 + 8 * eg + e;
        if (row < M) {
            *(float4*)(Ca + (size_t)row * Dk + c0) = acc[0][e];
            if constexpr (NW > 1) *(float4*)(Cb + (size_t)row * Dk + c0) = acc[1][e];
            if constexpr (NW > 2) *(float4*)(Cc + (size_t)row * Dk + c0) = acc[2][e];
        }
    }
}

// ---------------------------------------------------------------------------
// Small GEMM for G-row matrices: C[M,ncols] = A[M,256] @ B (+bias)
// ---------------------------------------------------------------------------
template <int ROWS>
__global__ void k_gemm(const float* __restrict__ A,
                       const float* __restrict__ B, int ldb,
                       const float* __restrict__ bias,
                       float* __restrict__ C, int ldc, int M) {
    __shared__ float Ald[ROWS][Dk];
    const int t = threadIdx.x;
    const int r0 = blockIdx.x * ROWS;
#pragma unroll
    for (int i = 0; i < ROWS; ++i)
        Ald[i][t] = (r0 + i < M) ? A[(size_t)(r0 + i) * Dk + t] : 0.0f;
    __syncthreads();

    const int c = blockIdx.y * 256 + t;
    float acc[ROWS];
    const float bi = bias ? bias[c] : 0.0f;
#pragma unroll
    for (int e = 0; e < ROWS; ++e) acc[e] = bi;

    for (int k = 0; k < Dk; k += 4) {
        const float w0 = B[(size_t)(k + 0) * ldb + c];
        const float w1 = B[(size_t)(k + 1) * ldb + c];
        const float w2 = B[(size_t)(k + 2) * ldb + c];
        const float w3 = B[(size_t)(k + 3) * ldb + c];
#pragma unroll
        for (int e = 0; e < ROWS; ++e) {
            const float4 a = *reinterpret_cast<const float4*>(&Ald[e][k]);
            acc[e] = fmaf(a.x, w0, acc[e]);
            acc[e] = fmaf(a.y, w1, acc[e]);
            acc[e] = fmaf(a.z, w2, acc[e]);
            acc[e] = fmaf(a.w, w3, acc[e]);
        }
    }
#pragma unroll
    for (int e = 0; e < ROWS; ++e)
        if (r0 + e < M) C[(size_t)(r0 + e) * ldc + c] = acc[e];
}

// fc: C[M,256] = A[M,64] @ B[64,256] + bias
__global__ void k_fc(const float* __restrict__ A, const float* __restrict__ B,
                     const float* __restrict__ bias, float* __restrict__ C, int M) {
    __shared__ float Ald[32][F];
    const int t = threadIdx.x;
    const int r0 = blockIdx.x * 32;
    for (int i = t; i < 32 * F; i += 256) {
        int r = i >> 6, k = i & 63;
        Ald[r][k] = (r0 + r < M) ? A[(size_t)(r0 + r) * F + k] : 0.0f;
    }
    __syncthreads();
    const int c = t;
    float acc[32];
    const float bi = bias[c];
#pragma unroll
    for (int e = 0; e < 32; ++e) acc[e] = bi;
    for (int k = 0; k < F; k += 4) {
        const float w0 = B[(size_t)(k + 0) * Dk + c];
        const float w1 = B[(size_t)(k + 1) * Dk + c];
        const float w2 = B[(size_t)(k + 2) * Dk + c];
        const float w3 = B[(size_t)(k + 3) * Dk + c];
#pragma unroll
        for (int e = 0; e < 32; ++e) {
            const float4 a = *reinterpret_cast<const float4*>(&Ald[e][k]);
            acc[e] = fmaf(a.x, w0, acc[e]);
            acc[e] = fmaf(a.y, w1, acc[e]);
            acc[e] = fmaf(a.z, w2, acc[e]);
            acc[e] = fmaf(a.w, w3, acc[e]);
        }
    }
#pragma unroll
    for (int e = 0; e < 32; ++e)
        if (r0 + e < M) C[(size_t)(r0 + e) * Dk + e * 0 + c] = acc[e];
}

// ---------------------------------------------------------------------------
// Readout node pass: gw = sigmoid(xr[n]+gfr[b]); gf_new[b] += gw*x[n];
// gnorm[b] += ||gw||. One wave per node.
// ---------------------------------------------------------------------------
__global__ void k_readout_node(const float* __restrict__ x, const float* __restrict__ xr,
                               const float* __restrict__ gfr, const int* __restrict__ batch,
                               float* __restrict__ gf_new, float* __restrict__ gnorm) {
    const int t = threadIdx.x;
    const int w = t >> 6, lane = t & 63;
    const int n = blockIdx.x * 4 + w;
    const int b = batch[n];
    float ss = 0.0f;
#pragma unroll
    for (int j = 0; j < 4; ++j) {
        const int c = lane + j * 64;
        const float g = sigmoidf_(xr[(size_t)n * Dk + c] + gfr[(size_t)b * Dk + c]);
        atomicAdd(&gf_new[(size_t)b * Dk + c], g * x[(size_t)n * Dk + c]);
        ss += g * g;
    }
    ss += __shfl_xor(ss, 1, 64);
    ss += __shfl_xor(ss, 2, 64);
    ss += __shfl_xor(ss, 4, 64);
    ss += __shfl_xor(ss, 8, 64);
    ss += __shfl_xor(ss, 16, 64);
    ss += __shfl_xor(ss, 32, 64);
    if (lane == 0) atomicAdd(&gnorm[b], sqrtf(ss));
}

__global__ void k_cnt(const int* __restrict__ batch, float* __restrict__ gcnt) {
    const int n = blockIdx.x * 256 + threadIdx.x;
    if (n < N) atomicAdd(&gcnt[batch[n]], 1.0f);
}

__global__ void k_ggl(const float* __restrict__ gnorm, const float* __restrict__ gcnt,
                      float* __restrict__ out) {
    const int t = threadIdx.x;  // 64 threads
    float v = gnorm[t] / fmaxf(gcnt[t], 1.0f);
#pragma unroll
    for (int off = 32; off; off >>= 1) v += __shfl_xor(v, off, 64);
    if (t == 0) *out = v * (1.0f / G);
}

// transpose in[rows,cols] -> out[cols,rows]
__global__ void k_transpose(const float* __restrict__ in, float* __restrict__ out,
                            int rows, int cols) {
    const int idx = blockIdx.x * 256 + threadIdx.x;
    if (idx < rows * cols) {
        const int r = idx / cols, c = idx % cols;
        out[(size_t)c * rows + r] = in[(size_t)r * cols + c];
    }
}

// GRU elementwise combine (gi, gh are [G,768]); gf updated in place.
__global__ void k_gru_ew(const float* __restrict__ gi, const float* __restrict__ gh,
                         float* __restrict__ gf) {
    const int g = blockIdx.x, d = threadIdx.x;
    const float* Gi = gi + (size_t)g * 768;
    const float* Gh = gh + (size_t)g * 768;
    const float h = gf[(size_t)g * Dk + d];
    const float r = sigmoidf_(Gi[d] + Gh[d]);
    const float z = sigmoidf_(Gi[256 + d] + Gh[256 + d]);
    const float nn = tanhf(Gi[512 + d] + r * Gh[512 + d]);
    gf[(size_t)g * Dk + d] = (1.0f - z) * nn + z * h;
}

// BatchNorm (training stats over G graphs) -> xn
__global__ void k_bn(const float* __restrict__ gf, const float* __restrict__ bg,
                     const float* __restrict__ bb, float* __restrict__ xn) {
    const int f = threadIdx.x;
    float mu = 0.0f;
    for (int g = 0; g < G; ++g) mu += gf[(size_t)g * Dk + f];
    mu *= (1.0f / G);
    float var = 0.0f;
    for (int g = 0; g < G; ++g) {
        const float d = gf[(size_t)g * Dk + f] - mu;
        var += d * d;
    }
    var *= (1.0f / G);
    const float inv = (1.0f / sqrtf(var + 1e-5f)) * bg[f];
    const float bet = bb[f];
    for (int g = 0; g < G; ++g)
        xn[(size_t)g * Dk + f] = (gf[(size_t)g * Dk + f] - mu) * inv + bet;
}

__global__ void k_clf1(const float* __restrict__ xn, const float* __restrict__ W,
                       const float* __restrict__ b, float* __restrict__ out) {
    __shared__ float row[Dk];
    const int g = blockIdx.x, t = threadIdx.x;
    row[t] = xn[(size_t)g * Dk + t];
    __syncthreads();
    float acc = b[t];
    for (int k = 0; k < Dk; k += 4) {
        const float4 a = *reinterpret_cast<const float4*>(&row[k]);
        acc = fmaf(a.x, W[(size_t)(k + 0) * HID + t], acc);
        acc = fmaf(a.y, W[(size_t)(k + 1) * HID + t], acc);
        acc = fmaf(a.z, W[(size_t)(k + 2) * HID + t], acc);
        acc = fmaf(a.w, W[(size_t)(k + 3) * HID + t], acc);
    }
    out[(size_t)g * HID + t] = leakyf_(acc);
}

__global__ void k_clf2(const float* __restrict__ h, const float* __restrict__ W,
                       const float* __restrict__ b, float* __restrict__ out) {
    __shared__ float row[HID];
    __shared__ float lg[NCLS];
    const int g = blockIdx.x, t = threadIdx.x;
    row[t] = h[(size_t)g * HID + t];
    __syncthreads();
    if (t < NCLS) {
        float acc = b[t];
        for (int k = 0; k < HID; ++k) acc = fmaf(row[k], W[(size_t)k * NCLS + t], acc);
        lg[t] = acc;
    }
    __syncthreads();
    if (t == 0) {
        float m = lg[0];
        for (int i = 1; i < NCLS; ++i) m = fmaxf(m, lg[i]);
        float s = 0.0f;
        for (int i = 0; i < NCLS; ++i) s += expf(lg[i] - m);
        const float ls = logf(s) + m;
        for (int i = 0; i < NCLS; ++i) out[(size_t)g * NCLS + i] = lg[i] - ls;
    }
}

// ---------------------------------------------------------------------------
extern "C" void kernel_launch(void* const* d_in, const int* in_sizes, int n_in,
                              void* d_out, int out_size, void* d_ws, size_t ws_size,
                              hipStream_t stream) {
    const float* x_in  = (const float*)d_in[0];
    const int*   ei    = (const int*)d_in[1];
    const int*   batch = (const int*)d_in[2];
    const float* fc_w  = (const float*)d_in[3];
    const float* fc_b  = (const float*)d_in[4];
    const float* mg1_w = (const float*)d_in[5];
    const float* mg1_b = (const float*)d_in[6];
    const float* mg2_w = (const float*)d_in[7];
    const float* mg2_b = (const float*)d_in[8];
    const float* gate_w = (const float*)d_in[9];
    const float* gate_b = (const float*)d_in[10];
    const float* rd_w  = (const float*)d_in[11];
    const float* rd_b  = (const float*)d_in[12];
    const float* gru_wih = (const float*)d_in[13];
    const float* gru_whh = (const float*)d_in[14];
    const float* gru_bih = (const float*)d_in[15];
    const float* gru_bhh = (const float*)d_in[16];
    const float* bn_g  = (const float*)d_in[17];
    const float* bn_b  = (const float*)d_in[18];
    const float* clf1_w = (const float*)d_in[19];
    const float* clf1_b = (const float*)d_in[20];
    const float* clf2_w = (const float*)d_in[21];
    const float* clf2_b = (const float*)d_in[22];

    float* ws = (float*)d_ws;
    size_t off = 0;
    float* cur0 = ws + off; off += (size_t)N * Dk;
    float* cur1 = ws + off; off += (size_t)N * Dk;
    float* xa   = ws + off; off += (size_t)N * Dk;
    float* xb   = ws + off; off += (size_t)N * Dk;
    float* xr   = ws + off; off += (size_t)N * Dk;
    float* gf   = ws + off; off += (size_t)G * Dk;
    float* gfn  = ws + off; off += (size_t)G * Dk;
    float* gfr  = ws + off; off += (size_t)G * Dk;
    float* gfc  = ws + off; off += (size_t)G * Dk;
    float* giB  = ws + off; off += (size_t)G * 768;
    float* ghB  = ws + off; off += (size_t)G * 768;
    float* gnorm = ws + off; off += G;
    float* gcnt  = ws + off; off += G;
    float* xn   = ws + off; off += (size_t)G * Dk;
    float* hcl  = ws + off; off += (size_t)G * HID;
    float* wihT = ws + off; off += (size_t)768 * Dk;
    float* whhT = ws + off; off += (size_t)768 * Dk;

    float* out_logits = (float*)d_out;
    float* out_lgl = out_logits + (size_t)G * NCLS;
    float* out_ggl = out_lgl + (size_t)E * L;

    hipMemsetAsync(gf, 0, (size_t)G * Dk * 4, stream);
    hipMemsetAsync(gcnt, 0, (size_t)G * 4, stream);
    k_cnt<<<(N + 255) / 256, 256, 0, stream>>>(batch, gcnt);
    k_transpose<<<(768 * Dk + 255) / 256, 256, 0, stream>>>(gru_wih, wihT, 768, Dk);
    k_transpose<<<(768 * Dk + 255) / 256, 256, 0, stream>>>(gru_whh, whhT, 768, Dk);

    k_fc<<<(N + 31) / 32, 256, 0, stream>>>(x_in, fc_w, fc_b, cur0, N);

    float* cur = cur0;
    float* nxt = cur1;
    const int nblk = (N + 31) / 32;

    auto readout = [&](const float* xcur, int ridx) {
        k_gemm<8><<<dim3(G / 8, 1), 256, 0, stream>>>(gf, rd_w + 256 * Dk, Dk, rd_b, gfr, Dk, G);
        hipMemsetAsync(gfn, 0, (size_t)G * Dk * 4, stream);
        hipMemsetAsync(gnorm, 0, (size_t)G * 4, stream);
        k_readout_node<<<N / 4, 256, 0, stream>>>(xcur, xr, gfr, batch, gfn, gnorm);
        k_gemm<8><<<dim3(G / 8, 3), 256, 0, stream>>>(gfn, wihT, 768, gru_bih, giB, 768, G);
        k_gemm<8><<<dim3(G / 8, 3), 256, 0, stream>>>(gf, whhT, 768, gru_bhh, ghB, 768, G);
        k_gru_ew<<<G, 256, 0, stream>>>(giB, ghB, gf);
        k_ggl<<<1, 64, 0, stream>>>(gnorm, gcnt, out_ggl + ridx);
    };

    for (int i = 0; i < L; ++i) {
        const float* W1 = mg1_w + (size_t)i * 768 * Dk;
        // xa = cur@W1a, xb = cur@W1b, xr = cur@rd_w  (one fused pass)
        k_mm<3><<<nblk, 256, 0, stream>>>(cur, N, W1, W1 + 256 * Dk, rd_w, xa, xb, xr);
        readout(cur, i);
        k_gemm<8><<<dim3(G / 8, 1), 256, 0, stream>>>(gf, W1 + 512 * Dk, Dk, mg1_b + i * Dk, gfc, Dk, G);
        hipMemsetAsync(nxt, 0, (size_t)N * Dk * 4, stream);
        k_edge_rt<<<E / 32, 256, 0, stream>>>(xa, xb, gfc, ei, batch,
                                              mg2_w + (size_t)i * Dk * Dk, mg2_b + i * Dk,
                                              gate_w + (size_t)i * Dk * Dk, gate_b + i * Dk,
                                              nxt, out_lgl, i);
        float* tmp = cur; cur = nxt; nxt = tmp;
    }
    k_mm<1><<<nblk, 256, 0, stream>>>(cur, N, rd_w, rd_w, rd_w, xr, nullptr, nullptr);
    readout(cur, L);

    k_bn<<<1, 256, 0, stream>>>(gf, bn_g, bn_b, xn);
    k_clf1<<<G, 256, 0, stream>>>(xn, clf1_w, clf1_b, hcl);
    k_clf2<<<G, 256, 0, stream>>>(hcl, clf2_w, clf2_b, out_logits);
}

// Round 4
// 2092.737 us; speedup vs baseline: 1.5969x; 1.2450x over previous
//
#include <hip/hip_runtime.h>
#include <math.h>

// Problem constants (match reference)
constexpr int N = 10000, E = 100000, G = 64;
constexpr int F = 64, Dk = 256, L = 3;
constexpr int HID = 256, NCLS = 10;

__device__ __forceinline__ float sigmoidf_(float x) {
    return 1.0f / (1.0f + __expf(-x));
}
__device__ __forceinline__ float leakyf_(float v) {
    return v > 0.0f ? v : 0.01f * v;
}

#define FMA4X4(aa, w0, w1, w2, w3, acc_)                                      \
    acc_.x = fmaf(aa.x, w0.x, acc_.x); acc_.y = fmaf(aa.x, w0.y, acc_.y);     \
    acc_.z = fmaf(aa.x, w0.z, acc_.z); acc_.w = fmaf(aa.x, w0.w, acc_.w);     \
    acc_.x = fmaf(aa.y, w1.x, acc_.x); acc_.y = fmaf(aa.y, w1.y, acc_.y);     \
    acc_.z = fmaf(aa.y, w1.z, acc_.z); acc_.w = fmaf(aa.y, w1.w, acc_.w);     \
    acc_.x = fmaf(aa.z, w2.x, acc_.x); acc_.y = fmaf(aa.z, w2.y, acc_.y);     \
    acc_.z = fmaf(aa.z, w2.z, acc_.z); acc_.w = fmaf(aa.z, w2.w, acc_.w);     \
    acc_.x = fmaf(aa.w, w3.x, acc_.x); acc_.y = fmaf(aa.w, w3.y, acc_.y);     \
    acc_.z = fmaf(aa.w, w3.z, acc_.z); acc_.w = fmaf(aa.w, w3.w, acc_.w);

// ---------------------------------------------------------------------------
// Edge sort by dst: histogram -> single-block scan -> scatter.
// ---------------------------------------------------------------------------
__global__ void k_hist(const int* __restrict__ ei, int* __restrict__ deg) {
    const int e = blockIdx.x * 256 + threadIdx.x;
    if (e < E) atomicAdd(&deg[ei[E + e]], 1);
}

__global__ void k_scan(const int* __restrict__ deg, int* __restrict__ cursor) {
    __shared__ int part[256];
    __shared__ int off[256];
    const int t = threadIdx.x;
    const int base = t * 40;  // 256*40 = 10240 >= N
    int s = 0;
    for (int i = 0; i < 40; ++i) {
        const int idx = base + i;
        if (idx < N) s += deg[idx];
    }
    part[t] = s;
    __syncthreads();
    if (t == 0) {
        int acc = 0;
        for (int i = 0; i < 256; ++i) { off[i] = acc; acc += part[i]; }
    }
    __syncthreads();
    int run = off[t];
    for (int i = 0; i < 40; ++i) {
        const int idx = base + i;
        if (idx < N) { cursor[idx] = run; run += deg[idx]; }
    }
}

__global__ void k_scatter(const int* __restrict__ ei, const int* __restrict__ batch,
                          int* __restrict__ cursor, int* __restrict__ src_s,
                          int* __restrict__ dst_s, int* __restrict__ gb_s,
                          int* __restrict__ eperm) {
    const int e = blockIdx.x * 256 + threadIdx.x;
    if (e < E) {
        const int d = ei[E + e];
        const int pos = atomicAdd(&cursor[d], 1);
        dst_s[pos] = d;
        src_s[pos] = ei[e];
        gb_s[pos] = batch[d];
        eperm[pos] = e;
    }
}

// ---------------------------------------------------------------------------
// Fused edge kernel (edges pre-sorted by dst):
//   h1  = leaky(xa[dst] + xb[src] + gfc[batch[dst]])   (gfc includes b1)
//   msg = leaky(h1 @ W2 + b2)
//   gp  = msg @ Wg + bg ; lw = sigmoid(gp)*msg
//   lgl[eperm[e], layer] = ||lw|| ; nxt[dst] += lw*msg (segmented atomics)
// 256 thr = 4 waves in 2x2 quadrants: wave covers 16 rows x 128 cols.
// Thread: 8 rows x 4 cols, acc float4[8]. A from LDS broadcast, W from global
// (L1/L2-resident, coalesced, no staging barriers).
// ---------------------------------------------------------------------------
__global__ __launch_bounds__(256, 4) void k_edge_rt(
    const float* __restrict__ xa, const float* __restrict__ xb,
    const float* __restrict__ gfc,
    const int* __restrict__ src_s, const int* __restrict__ dst_s,
    const int* __restrict__ gb_s, const int* __restrict__ eperm,
    const float* __restrict__ W2, const float* __restrict__ b2,
    const float* __restrict__ Wg, const float* __restrict__ bg,
    float* __restrict__ nxt, float* __restrict__ lgl, int layer) {
    __shared__ float tile[32][Dk];   // h1, then msg (32 KB)
    __shared__ int sdst[32];
    __shared__ float prow[2][32];

    const int t = threadIdx.x;
    // bijective chunked XCD swizzle: consecutive dst-ranges stay on one XCD
    constexpr int NBLK = E / 32;               // 3125
    constexpr int qq = NBLK / 8, rr = NBLK % 8;
    const int orig = blockIdx.x;
    const int xcd = orig & 7, pos = orig >> 3;
    const int bid = (xcd < rr ? xcd * (qq + 1) : rr * (qq + 1) + (xcd - rr) * qq) + pos;
    const int e0 = bid * 32;

    // ---- h1 tile: 8 threads per row, 8 float4 each ----
    {
        const int r = t >> 3, l8 = t & 7;
        const int d = dst_s[e0 + r], s = src_s[e0 + r], b = gb_s[e0 + r];
        const float4* pa = (const float4*)(xa + (size_t)d * Dk);
        const float4* pb = (const float4*)(xb + (size_t)s * Dk);
        const float4* pg = (const float4*)(gfc + (size_t)b * Dk);
        float4* pt = (float4*)(&tile[r][0]);
#pragma unroll
        for (int j = 0; j < 8; ++j) {
            const int ci = l8 + 8 * j;
            const float4 va = pa[ci], vb = pb[ci], vg = pg[ci];
            float4 v;
            v.x = leakyf_(va.x + vb.x + vg.x);
            v.y = leakyf_(va.y + vb.y + vg.y);
            v.z = leakyf_(va.z + vb.z + vg.z);
            v.w = leakyf_(va.w + vb.w + vg.w);
            pt[ci] = v;
        }
    }
    if (t < 32) sdst[t] = dst_s[e0 + t];
    __syncthreads();

    const int lane = t & 63, wv = t >> 6;
    const int rbase = (wv >> 1) * 16 + (lane >> 5) * 8;  // thread's 8 rows
    const int c0 = (wv & 1) * 128 + (lane & 31) * 4;     // thread's 4 cols
    float4 acc[8];

    // ============ GEMM1: msg = leaky(h1 @ W2 + b2), W from global ============
    {
        const float4 bi = *(const float4*)(b2 + c0);
#pragma unroll
        for (int e = 0; e < 8; ++e) acc[e] = bi;
    }
#pragma unroll 2
    for (int k = 0; k < Dk; k += 4) {
        const float4 w0 = *(const float4*)(W2 + (size_t)(k + 0) * Dk + c0);
        const float4 w1 = *(const float4*)(W2 + (size_t)(k + 1) * Dk + c0);
        const float4 w2 = *(const float4*)(W2 + (size_t)(k + 2) * Dk + c0);
        const float4 w3 = *(const float4*)(W2 + (size_t)(k + 3) * Dk + c0);
#pragma unroll
        for (int e = 0; e < 8; ++e) {
            const float4 a = *(const float4*)(&tile[rbase + e][k]);
            FMA4X4(a, w0, w1, w2, w3, acc[e]);
        }
    }
    __syncthreads();  // all h1 reads done before overwrite
#pragma unroll
    for (int e = 0; e < 8; ++e) {
        float4 m;
        m.x = leakyf_(acc[e].x);
        m.y = leakyf_(acc[e].y);
        m.z = leakyf_(acc[e].z);
        m.w = leakyf_(acc[e].w);
        *(float4*)(&tile[rbase + e][c0]) = m;
    }
    __syncthreads();  // msg tile complete

    // ============ GEMM2: gp = msg @ Wg + bg ============
    {
        const float4 bi = *(const float4*)(bg + c0);
#pragma unroll
        for (int e = 0; e < 8; ++e) acc[e] = bi;
    }
#pragma unroll 2
    for (int k = 0; k < Dk; k += 4) {
        const float4 w0 = *(const float4*)(Wg + (size_t)(k + 0) * Dk + c0);
        const float4 w1 = *(const float4*)(Wg + (size_t)(k + 1) * Dk + c0);
        const float4 w2 = *(const float4*)(Wg + (size_t)(k + 2) * Dk + c0);
        const float4 w3 = *(const float4*)(Wg + (size_t)(k + 3) * Dk + c0);
#pragma unroll
        for (int e = 0; e < 8; ++e) {
            const float4 a = *(const float4*)(&tile[rbase + e][k]);
            FMA4X4(a, w0, w1, w2, w3, acc[e]);
        }
    }

    // ---- epilogue: lw = sigmoid(gp)*msg; segmented scatter; row norms ----
    float srow[8];
    float4 vsum = make_float4(0.f, 0.f, 0.f, 0.f);
#pragma unroll
    for (int e = 0; e < 8; ++e) {
        const float4 m = *(const float4*)(&tile[rbase + e][c0]);
        float4 lw;
        lw.x = sigmoidf_(acc[e].x) * m.x;
        lw.y = sigmoidf_(acc[e].y) * m.y;
        lw.z = sigmoidf_(acc[e].z) * m.z;
        lw.w = sigmoidf_(acc[e].w) * m.w;
        vsum.x += lw.x * m.x;
        vsum.y += lw.y * m.y;
        vsum.z += lw.z * m.z;
        vsum.w += lw.w * m.w;
        const int d = sdst[rbase + e];
        const bool flush = (e == 7) || (sdst[rbase + e + 1] != d);
        if (flush) {
            float* base = nxt + (size_t)d * Dk + c0;
            atomicAdd(base + 0, vsum.x);
            atomicAdd(base + 1, vsum.y);
            atomicAdd(base + 2, vsum.z);
            atomicAdd(base + 3, vsum.w);
            vsum = make_float4(0.f, 0.f, 0.f, 0.f);
        }
        float s = lw.x * lw.x + lw.y * lw.y + lw.z * lw.z + lw.w * lw.w;
        s += __shfl_xor(s, 1, 64);
        s += __shfl_xor(s, 2, 64);
        s += __shfl_xor(s, 4, 64);
        s += __shfl_xor(s, 8, 64);
        s += __shfl_xor(s, 16, 64);  // reduced over the 32-lane half (same row)
        srow[e] = s;
    }
    if ((lane & 31) == 0) {
        const int wc = wv & 1;
#pragma unroll
        for (int e = 0; e < 8; ++e) prow[wc][rbase + e] = srow[e];
    }
    __syncthreads();
    if (t < 32) {
        const float s = prow[0][t] + prow[1][t];
        lgl[(size_t)eperm[e0 + t] * L + layer] = sqrtf(s);
    }
}

// ---------------------------------------------------------------------------
// Node GEMM, NW weight streams sharing one A tile (sequential passes):
//   C_w[M,256] = A[M,256] @ W_w[256,256]
// Same 2x2 wave-quadrant tiling; W from global.
// ---------------------------------------------------------------------------
template <int NW>
__global__ __launch_bounds__(256, 4) void k_mm(
    const float* __restrict__ A, int M,
    const float* __restrict__ Wp0, const float* __restrict__ Wp1,
    const float* __restrict__ Wp2,
    float* __restrict__ Cp0, float* __restrict__ Cp1, float* __restrict__ Cp2) {
    __shared__ float tile[32][Dk];
    const int t = threadIdx.x;
    const int r0 = blockIdx.x * 32;
    {
        const int r = t >> 3, l8 = t & 7;
        int row = r0 + r;
        if (row >= M) row = M - 1;
        const float4* pa = (const float4*)(A + (size_t)row * Dk);
        float4* pt = (float4*)(&tile[r][0]);
#pragma unroll
        for (int j = 0; j < 8; ++j) {
            const int ci = l8 + 8 * j;
            pt[ci] = pa[ci];
        }
    }
    __syncthreads();

    const int lane = t & 63, wv = t >> 6;
    const int rbase = (wv >> 1) * 16 + (lane >> 5) * 8;
    const int c0 = (wv & 1) * 128 + (lane & 31) * 4;

    const float* Ws[3] = {Wp0, Wp1, Wp2};
    float* Cs[3] = {Cp0, Cp1, Cp2};
#pragma unroll
    for (int w = 0; w < NW; ++w) {
        const float* Wp = Ws[w];
        float4 acc[8];
#pragma unroll
        for (int e = 0; e < 8; ++e) acc[e] = make_float4(0.f, 0.f, 0.f, 0.f);
#pragma unroll 2
        for (int k = 0; k < Dk; k += 4) {
            const float4 w0 = *(const float4*)(Wp + (size_t)(k + 0) * Dk + c0);
            const float4 w1 = *(const float4*)(Wp + (size_t)(k + 1) * Dk + c0);
            const float4 w2 = *(const float4*)(Wp + (size_t)(k + 2) * Dk + c0);
            const float4 w3 = *(const float4*)(Wp + (size_t)(k + 3) * Dk + c0);
#pragma unroll
            for (int e = 0; e < 8; ++e) {
                const float4 a = *(const float4*)(&tile[rbase + e][k]);
                FMA4X4(a, w0, w1, w2, w3, acc[e]);
            }
        }
        float* Cp = Cs[w];
#pragma unroll
        for (int e = 0; e < 8; ++e) {
            const int row = r0 + rbase + e;
            if (row < M) *(float4*)(Cp + (size_t)row * Dk + c0) = acc[e];
        }
    }
}

// ---------------------------------------------------------------------------
// Small GEMM for G-row matrices: C[M,ncols] = A[M,256] @ B (+bias)
// ---------------------------------------------------------------------------
template <int ROWS>
__global__ void k_gemm(const float* __restrict__ A,
                       const float* __restrict__ B, int ldb,
                       const float* __restrict__ bias,
                       float* __restrict__ C, int ldc, int M) {
    __shared__ float Ald[ROWS][Dk];
    const int t = threadIdx.x;
    const int r0 = blockIdx.x * ROWS;
#pragma unroll
    for (int i = 0; i < ROWS; ++i)
        Ald[i][t] = (r0 + i < M) ? A[(size_t)(r0 + i) * Dk + t] : 0.0f;
    __syncthreads();

    const int c = blockIdx.y * 256 + t;
    float acc[ROWS];
    const float bi = bias ? bias[c] : 0.0f;
#pragma unroll
    for (int e = 0; e < ROWS; ++e) acc[e] = bi;

    for (int k = 0; k < Dk; k += 4) {
        const float w0 = B[(size_t)(k + 0) * ldb + c];
        const float w1 = B[(size_t)(k + 1) * ldb + c];
        const float w2 = B[(size_t)(k + 2) * ldb + c];
        const float w3 = B[(size_t)(k + 3) * ldb + c];
#pragma unroll
        for (int e = 0; e < ROWS; ++e) {
            const float4 a = *reinterpret_cast<const float4*>(&Ald[e][k]);
            acc[e] = fmaf(a.x, w0, acc[e]);
            acc[e] = fmaf(a.y, w1, acc[e]);
            acc[e] = fmaf(a.z, w2, acc[e]);
            acc[e] = fmaf(a.w, w3, acc[e]);
        }
    }
#pragma unroll
    for (int e = 0; e < ROWS; ++e)
        if (r0 + e < M) C[(size_t)(r0 + e) * ldc + c] = acc[e];
}

// fc: C[M,256] = A[M,64] @ B[64,256] + bias
__global__ void k_fc(const float* __restrict__ A, const float* __restrict__ B,
                     const float* __restrict__ bias, float* __restrict__ C, int M) {
    __shared__ float Ald[32][F];
    const int t = threadIdx.x;
    const int r0 = blockIdx.x * 32;
    for (int i = t; i < 32 * F; i += 256) {
        int r = i >> 6, k = i & 63;
        Ald[r][k] = (r0 + r < M) ? A[(size_t)(r0 + r) * F + k] : 0.0f;
    }
    __syncthreads();
    const int c = t;
    float acc[32];
    const float bi = bias[c];
#pragma unroll
    for (int e = 0; e < 32; ++e) acc[e] = bi;
    for (int k = 0; k < F; k += 4) {
        const float w0 = B[(size_t)(k + 0) * Dk + c];
        const float w1 = B[(size_t)(k + 1) * Dk + c];
        const float w2 = B[(size_t)(k + 2) * Dk + c];
        const float w3 = B[(size_t)(k + 3) * Dk + c];
#pragma unroll
        for (int e = 0; e < 32; ++e) {
            const float4 a = *reinterpret_cast<const float4*>(&Ald[e][k]);
            acc[e] = fmaf(a.x, w0, acc[e]);
            acc[e] = fmaf(a.y, w1, acc[e]);
            acc[e] = fmaf(a.z, w2, acc[e]);
            acc[e] = fmaf(a.w, w3, acc[e]);
        }
    }
#pragma unroll
    for (int e = 0; e < 32; ++e)
        if (r0 + e < M) C[(size_t)(r0 + e) * Dk + c] = acc[e];
}

// ---------------------------------------------------------------------------
// Readout node pass (batch sorted): run-accumulated scatter.
// Phase A: thread-per-col accumulates g*x over node range, flush per graph.
// Phase B: per-node ||gw|| with run-accumulated gnorm atomics.
// ---------------------------------------------------------------------------
constexpr int RNPB = 40;  // nodes per block, 250 blocks
__global__ void k_readout_node(const float* __restrict__ x, const float* __restrict__ xr,
                               const float* __restrict__ gfr, const int* __restrict__ batch,
                               float* __restrict__ gfn, float* __restrict__ gnorm) {
    const int t = threadIdx.x;
    const int n0 = blockIdx.x * RNPB;
    {   // phase A
        const int c = t;
        float acc = 0.0f;
        int bprev = batch[n0];
        for (int i = 0; i < RNPB; ++i) {
            const int n = n0 + i;
            const int b = batch[n];
            if (b != bprev) {
                atomicAdd(&gfn[(size_t)bprev * Dk + c], acc);
                acc = 0.0f;
                bprev = b;
            }
            const float g = sigmoidf_(xr[(size_t)n * Dk + c] + gfr[(size_t)b * Dk + c]);
            acc = fmaf(g, x[(size_t)n * Dk + c], acc);
        }
        atomicAdd(&gfn[(size_t)bprev * Dk + c], acc);
    }
    {   // phase B
        const int lane = t & 63, wv = t >> 6;
        float rs = 0.0f;
        int bprev = -1;
        for (int i = wv; i < RNPB; i += 4) {
            const int n = n0 + i;
            const int b = batch[n];
            const float4 vr = *(const float4*)(xr + (size_t)n * Dk + lane * 4);
            const float4 vg = *(const float4*)(gfr + (size_t)b * Dk + lane * 4);
            const float g0 = sigmoidf_(vr.x + vg.x), g1 = sigmoidf_(vr.y + vg.y);
            const float g2 = sigmoidf_(vr.z + vg.z), g3 = sigmoidf_(vr.w + vg.w);
            float s = g0 * g0 + g1 * g1 + g2 * g2 + g3 * g3;
            s += __shfl_xor(s, 1, 64);
            s += __shfl_xor(s, 2, 64);
            s += __shfl_xor(s, 4, 64);
            s += __shfl_xor(s, 8, 64);
            s += __shfl_xor(s, 16, 64);
            s += __shfl_xor(s, 32, 64);
            if (lane == 0) {
                if (b != bprev && bprev >= 0) {
                    atomicAdd(&gnorm[bprev], rs);
                    rs = 0.0f;
                }
                bprev = b;
                rs += sqrtf(s);
            }
        }
        if (lane == 0 && bprev >= 0) atomicAdd(&gnorm[bprev], rs);
    }
}

__global__ void k_cnt(const int* __restrict__ batch, float* __restrict__ gcnt) {
    const int n = blockIdx.x * 256 + threadIdx.x;
    if (n < N) atomicAdd(&gcnt[batch[n]], 1.0f);
}

__global__ void k_ggl(const float* __restrict__ gnorm, const float* __restrict__ gcnt,
                      float* __restrict__ out) {
    const int t = threadIdx.x;  // 64 threads
    float v = gnorm[t] / fmaxf(gcnt[t], 1.0f);
#pragma unroll
    for (int off = 32; off; off >>= 1) v += __shfl_xor(v, off, 64);
    if (t == 0) *out = v * (1.0f / G);
}

// transpose in[rows,cols] -> out[cols,rows]
__global__ void k_transpose(const float* __restrict__ in, float* __restrict__ out,
                            int rows, int cols) {
    const int idx = blockIdx.x * 256 + threadIdx.x;
    if (idx < rows * cols) {
        const int r = idx / cols, c = idx % cols;
        out[(size_t)c * rows + r] = in[(size_t)r * cols + c];
    }
}

// GRU elementwise combine (gi, gh are [G,768]); gf updated in place.
__global__ void k_gru_ew(const float* __restrict__ gi, const float* __restrict__ gh,
                         float* __restrict__ gf) {
    const int g = blockIdx.x, d = threadIdx.x;
    const float* Gi = gi + (size_t)g * 768;
    const float* Gh = gh + (size_t)g * 768;
    const float h = gf[(size_t)g * Dk + d];
    const float r = sigmoidf_(Gi[d] + Gh[d]);
    const float z = sigmoidf_(Gi[256 + d] + Gh[256 + d]);
    const float nn = tanhf(Gi[512 + d] + r * Gh[512 + d]);
    gf[(size_t)g * Dk + d] = (1.0f - z) * nn + z * h;
}

// BatchNorm (training stats over G graphs) -> xn
__global__ void k_bn(const float* __restrict__ gf, const float* __restrict__ bg,
                     const float* __restrict__ bb, float* __restrict__ xn) {
    const int f = threadIdx.x;
    float mu = 0.0f;
    for (int g = 0; g < G; ++g) mu += gf[(size_t)g * Dk + f];
    mu *= (1.0f / G);
    float var = 0.0f;
    for (int g = 0; g < G; ++g) {
        const float d = gf[(size_t)g * Dk + f] - mu;
        var += d * d;
    }
    var *= (1.0f / G);
    const float inv = (1.0f / sqrtf(var + 1e-5f)) * bg[f];
    const float bet = bb[f];
    for (int g = 0; g < G; ++g)
        xn[(size_t)g * Dk + f] = (gf[(size_t)g * Dk + f] - mu) * inv + bet;
}

__global__ void k_clf1(const float* __restrict__ xn, const float* __restrict__ W,
                       const float* __restrict__ b, float* __restrict__ out) {
    __shared__ float row[Dk];
    const int g = blockIdx.x, t = threadIdx.x;
    row[t] = xn[(size_t)g * Dk + t];
    __syncthreads();
    float acc = b[t];
    for (int k = 0; k < Dk; k += 4) {
        const float4 a = *reinterpret_cast<const float4*>(&row[k]);
        acc = fmaf(a.x, W[(size_t)(k + 0) * HID + t], acc);
        acc = fmaf(a.y, W[(size_t)(k + 1) * HID + t], acc);
        acc = fmaf(a.z, W[(size_t)(k + 2) * HID + t], acc);
        acc = fmaf(a.w, W[(size_t)(k + 3) * HID + t], acc);
    }
    out[(size_t)g * HID + t] = leakyf_(acc);
}

__global__ void k_clf2(const float* __restrict__ h, const float* __restrict__ W,
                       const float* __restrict__ b, float* __restrict__ out) {
    __shared__ float row[HID];
    __shared__ float lg[NCLS];
    const int g = blockIdx.x, t = threadIdx.x;
    row[t] = h[(size_t)g * HID + t];
    __syncthreads();
    if (t < NCLS) {
        float acc = b[t];
        for (int k = 0; k < HID; ++k) acc = fmaf(row[k], W[(size_t)k * NCLS + t], acc);
        lg[t] = acc;
    }
    __syncthreads();
    if (t == 0) {
        float m = lg[0];
        for (int i = 1; i < NCLS; ++i) m = fmaxf(m, lg[i]);
        float s = 0.0f;
        for (int i = 0; i < NCLS; ++i) s += expf(lg[i] - m);
        const float ls = logf(s) + m;
        for (int i = 0; i < NCLS; ++i) out[(size_t)g * NCLS + i] = lg[i] - ls;
    }
}

// ---------------------------------------------------------------------------
extern "C" void kernel_launch(void* const* d_in, const int* in_sizes, int n_in,
                              void* d_out, int out_size, void* d_ws, size_t ws_size,
                              hipStream_t stream) {
    const float* x_in  = (const float*)d_in[0];
    const int*   ei    = (const int*)d_in[1];
    const int*   batch = (const int*)d_in[2];
    const float* fc_w  = (const float*)d_in[3];
    const float* fc_b  = (const float*)d_in[4];
    const float* mg1_w = (const float*)d_in[5];
    const float* mg1_b = (const float*)d_in[6];
    const float* mg2_w = (const float*)d_in[7];
    const float* mg2_b = (const float*)d_in[8];
    const float* gate_w = (const float*)d_in[9];
    const float* gate_b = (const float*)d_in[10];
    const float* rd_w  = (const float*)d_in[11];
    const float* rd_b  = (const float*)d_in[12];
    const float* gru_wih = (const float*)d_in[13];
    const float* gru_whh = (const float*)d_in[14];
    const float* gru_bih = (const float*)d_in[15];
    const float* gru_bhh = (const float*)d_in[16];
    const float* bn_g  = (const float*)d_in[17];
    const float* bn_b  = (const float*)d_in[18];
    const float* clf1_w = (const float*)d_in[19];
    const float* clf1_b = (const float*)d_in[20];
    const float* clf2_w = (const float*)d_in[21];
    const float* clf2_b = (const float*)d_in[22];

    float* ws = (float*)d_ws;
    size_t off = 0;
    float* cur0 = ws + off; off += (size_t)N * Dk;
    float* cur1 = ws + off; off += (size_t)N * Dk;
    float* xa   = ws + off; off += (size_t)N * Dk;
    float* xb   = ws + off; off += (size_t)N * Dk;
    float* xr   = ws + off; off += (size_t)N * Dk;
    float* gf   = ws + off; off += (size_t)G * Dk;
    float* gfn  = ws + off; off += (size_t)G * Dk;
    float* gfr  = ws + off; off += (size_t)G * Dk;
    float* gfc  = ws + off; off += (size_t)G * Dk;
    float* giB  = ws + off; off += (size_t)G * 768;
    float* ghB  = ws + off; off += (size_t)G * 768;
    float* gnorm = ws + off; off += G;
    float* gcnt  = ws + off; off += G;
    float* xn   = ws + off; off += (size_t)G * Dk;
    float* hcl  = ws + off; off += (size_t)G * HID;
    float* wihT = ws + off; off += (size_t)768 * Dk;
    float* whhT = ws + off; off += (size_t)768 * Dk;
    int* ideg   = (int*)(ws + off); off += N;
    int* icur   = (int*)(ws + off); off += N;
    int* src_s  = (int*)(ws + off); off += E;
    int* dst_s  = (int*)(ws + off); off += E;
    int* gb_s   = (int*)(ws + off); off += E;
    int* eperm  = (int*)(ws + off); off += E;

    float* out_logits = (float*)d_out;
    float* out_lgl = out_logits + (size_t)G * NCLS;
    float* out_ggl = out_lgl + (size_t)E * L;

    hipMemsetAsync(gf, 0, (size_t)G * Dk * 4, stream);
    hipMemsetAsync(gcnt, 0, (size_t)G * 4, stream);
    hipMemsetAsync(ideg, 0, (size_t)N * 4, stream);
    k_cnt<<<(N + 255) / 256, 256, 0, stream>>>(batch, gcnt);
    k_hist<<<(E + 255) / 256, 256, 0, stream>>>(ei, ideg);
    k_scan<<<1, 256, 0, stream>>>(ideg, icur);
    k_scatter<<<(E + 255) / 256, 256, 0, stream>>>(ei, batch, icur, src_s, dst_s, gb_s, eperm);
    k_transpose<<<(768 * Dk + 255) / 256, 256, 0, stream>>>(gru_wih, wihT, 768, Dk);
    k_transpose<<<(768 * Dk + 255) / 256, 256, 0, stream>>>(gru_whh, whhT, 768, Dk);

    k_fc<<<(N + 31) / 32, 256, 0, stream>>>(x_in, fc_w, fc_b, cur0, N);

    float* cur = cur0;
    float* nxt = cur1;
    const int nblk = (N + 31) / 32;

    auto readout = [&](const float* xcur, int ridx) {
        k_gemm<8><<<dim3(G / 8, 1), 256, 0, stream>>>(gf, rd_w + 256 * Dk, Dk, rd_b, gfr, Dk, G);
        hipMemsetAsync(gfn, 0, (size_t)G * Dk * 4, stream);
        hipMemsetAsync(gnorm, 0, (size_t)G * 4, stream);
        k_readout_node<<<N / RNPB, 256, 0, stream>>>(xcur, xr, gfr, batch, gfn, gnorm);
        k_gemm<8><<<dim3(G / 8, 3), 256, 0, stream>>>(gfn, wihT, 768, gru_bih, giB, 768, G);
        k_gemm<8><<<dim3(G / 8, 3), 256, 0, stream>>>(gf, whhT, 768, gru_bhh, ghB, 768, G);
        k_gru_ew<<<G, 256, 0, stream>>>(giB, ghB, gf);
        k_ggl<<<1, 64, 0, stream>>>(gnorm, gcnt, out_ggl + ridx);
    };

    for (int i = 0; i < L; ++i) {
        const float* W1 = mg1_w + (size_t)i * 768 * Dk;
        // xa = cur@W1a, xb = cur@W1b, xr = cur@rd_w  (one A-stage, 3 passes)
        k_mm<3><<<nblk, 256, 0, stream>>>(cur, N, W1, W1 + 256 * Dk, rd_w, xa, xb, xr);
        readout(cur, i);
        k_gemm<8><<<dim3(G / 8, 1), 256, 0, stream>>>(gf, W1 + 512 * Dk, Dk, mg1_b + i * Dk, gfc, Dk, G);
        hipMemsetAsync(nxt, 0, (size_t)N * Dk * 4, stream);
        k_edge_rt<<<E / 32, 256, 0, stream>>>(xa, xb, gfc, src_s, dst_s, gb_s, eperm,
                                              mg2_w + (size_t)i * Dk * Dk, mg2_b + i * Dk,
                                              gate_w + (size_t)i * Dk * Dk, gate_b + i * Dk,
                                              nxt, out_lgl, i);
        float* tmp = cur; cur = nxt; nxt = tmp;
    }
    k_mm<1><<<nblk, 256, 0, stream>>>(cur, N, rd_w, nullptr, nullptr, xr, nullptr, nullptr);
    readout(cur, L);

    k_bn<<<1, 256, 0, stream>>>(gf, bn_g, bn_b, xn);
    k_clf1<<<G, 256, 0, stream>>>(xn, clf1_w, clf1_b, hcl);
    k_clf2<<<G, 256, 0, stream>>>(hcl, clf2_w, clf2_b, out_logits);
}